// Round 9
// baseline (257.691 us; speedup 1.0000x reference)
//
#include <hip/hip_runtime.h>

typedef __attribute__((ext_vector_type(8))) short bf16x8;
typedef __attribute__((ext_vector_type(4))) float f32x4;

__device__ __forceinline__ unsigned short f2bf(float x) {
    union { float f; unsigned u; } v; v.f = x;
    unsigned r = v.u + 0x7FFFu + ((v.u >> 16) & 1u);
    return (unsigned short)(r >> 16);
}
__device__ __forceinline__ float bf2f(unsigned u) {
    union { unsigned u; float f; } v; v.u = u << 16;
    return v.f;
}

#define CHUNK 4096

// ---------- bucketed CSR build (bucket = dst>>8) ----------
__global__ __launch_bounds__(256) void k_bucket_count(const int* __restrict__ edst,
                                                      int* __restrict__ bcount, int E) {
    __shared__ int hist[256];
    int tid = threadIdx.x;
    hist[tid] = 0;
    __syncthreads();
    int e0 = blockIdx.x * CHUNK;
    int cnt = min(CHUNK, E - e0);
    for (int i = tid; i < cnt; i += 256) atomicAdd(&hist[edst[e0 + i] >> 8], 1);
    __syncthreads();
    if (hist[tid]) atomicAdd(&bcount[tid], hist[tid]);
}

__global__ __launch_bounds__(256) void k_bucket_scan(const int* __restrict__ bcount,
                                                     int* __restrict__ bbase,
                                                     int* __restrict__ bcursor, int E) {
    __shared__ int sh[256];
    int tid = threadIdx.x;
    int v = bcount[tid];
    sh[tid] = v;
    __syncthreads();
    for (int off = 1; off < 256; off <<= 1) {
        int t = (tid >= off) ? sh[tid - off] : 0;
        __syncthreads();
        sh[tid] += t;
        __syncthreads();
    }
    int excl = sh[tid] - v;
    bbase[tid] = excl;
    bcursor[tid] = excl;
    if (tid == 0) bbase[256] = E;
}

__global__ __launch_bounds__(256) void k_bucket_scatter(const int* __restrict__ esrc,
                                                        const int* __restrict__ edst,
                                                        int* __restrict__ bcursor,
                                                        unsigned* __restrict__ bsorted, int E) {
    __shared__ unsigned stage[CHUNK];
    __shared__ int hist[256], base[256], cur[256];
    int tid = threadIdx.x;
    hist[tid] = 0;
    __syncthreads();
    int e0 = blockIdx.x * CHUNK;
    int cnt = min(CHUNK, E - e0);
    for (int i = tid; i < cnt; i += 256) {
        int d = edst[e0 + i], s = esrc[e0 + i];
        stage[i] = ((unsigned)d << 16) | (unsigned)s;
        atomicAdd(&hist[d >> 8], 1);
    }
    __syncthreads();
    base[tid] = hist[tid] ? atomicAdd(&bcursor[tid], hist[tid]) : 0;
    cur[tid] = 0;
    __syncthreads();
    for (int i = tid; i < cnt; i += 256) {
        unsigned pk = stage[i];
        int b = pk >> 24;
        int p = base[b] + atomicAdd(&cur[b], 1);
        bsorted[p] = pk;
    }
}

// one block per bucket; csr stores PRE-SCALED uint offsets (src<<6)
__global__ __launch_bounds__(256) void k_bucket_csr(const unsigned* __restrict__ bsorted,
                                                    const int* __restrict__ bbase,
                                                    int* __restrict__ row_start,
                                                    float* __restrict__ dinv,
                                                    int* __restrict__ csr, int N, int E) {
    __shared__ int sh[256];
    __shared__ int cur[256];
    int tid = threadIdx.x;
    int b = blockIdx.x;
    int lo = bbase[b], hi = bbase[b + 1];
    sh[tid] = 0;
    __syncthreads();
    for (int i = lo + tid; i < hi; i += 256) atomicAdd(&sh[(bsorted[i] >> 16) & 255], 1);
    __syncthreads();
    int v = sh[tid];
    __syncthreads();
    sh[tid] = v;
    __syncthreads();
    for (int off = 1; off < 256; off <<= 1) {
        int t = (tid >= off) ? sh[tid - off] : 0;
        __syncthreads();
        sh[tid] += t;
        __syncthreads();
    }
    int excl = sh[tid] - v;
    int d = (b << 8) + tid;
    if (d < N) {
        row_start[d] = lo + excl;
        dinv[d] = 1.0f / (float)(v > 1 ? v : 1);
    }
    cur[tid] = lo + excl;
    __syncthreads();
    for (int i = lo + tid; i < hi; i += 256) {
        unsigned pk = bsorted[i];
        int p = atomicAdd(&cur[(pk >> 16) & 255], 1);
        csr[p] = (int)(pk & 0xffffu) << 6;
    }
    if (b == 0 && tid == 0) row_start[N] = E;
}

// ---------- merged weight transpose+convert ----------
__global__ __launch_bounds__(256) void k_wT_all(
    const float* __restrict__ Ws0, const float* __restrict__ Wn0,
    const float* __restrict__ Ws1, const float* __restrict__ Wn1,
    const float* __restrict__ Ws2, const float* __restrict__ Wn2,
    unsigned short* __restrict__ WT0s, unsigned short* __restrict__ WT0n,
    unsigned short* __restrict__ WT1s, unsigned short* __restrict__ WT1n,
    unsigned short* __restrict__ WT2) {
    int i = blockIdx.x * 256 + threadIdx.x;
    if (i < 16384)      { int j = i;         WT0s[j] = f2bf(Ws0[(j & 127) * 128 + (j >> 7)]); }
    else if (i < 32768) { int j = i - 16384; WT0n[j] = f2bf(Wn0[(j & 127) * 128 + (j >> 7)]); }
    else if (i < 49152) { int j = i - 32768; WT1s[j] = f2bf(Ws1[(j & 127) * 128 + (j >> 7)]); }
    else if (i < 65536) { int j = i - 49152; WT1n[j] = f2bf(Wn1[(j & 127) * 128 + (j >> 7)]); }
    else if (i < 73728) { int j = i - 65536; WT2[j] = f2bf(Ws2[(j & 127) * 64 + (j >> 7)]); }
    else if (i < 81920) { int j = i - 73728; WT2[8192 + j] = f2bf(Wn2[(j & 127) * 64 + (j >> 7)]); }
}

// ---------- layer-0 MFMA dual GEMM from fp32 features ----------
__global__ __launch_bounds__(256) void k_mfma_dual0(
    const float* __restrict__ Xf,
    const unsigned short* __restrict__ WsT, const unsigned short* __restrict__ WnT,
    const float* __restrict__ bias, unsigned short* __restrict__ Ab,
    unsigned short* __restrict__ Tb, int N) {
    __shared__ unsigned short xs[64][136];
    int tid = threadIdx.x;
    int br = blockIdx.x << 6;
    #pragma unroll
    for (int it = 0; it < 4; ++it) {
        int idx = tid + it * 256;
        int row = idx >> 4;
        int co = (idx & 15) << 3;
        int n = br + row;
        uint4 pk = make_uint4(0, 0, 0, 0);
        if (n < N) {
            float4 v0 = *(const float4*)(Xf + (size_t)n * 128 + co);
            float4 v1 = *(const float4*)(Xf + (size_t)n * 128 + co + 4);
            pk.x = (unsigned)f2bf(v0.x) | ((unsigned)f2bf(v0.y) << 16);
            pk.y = (unsigned)f2bf(v0.z) | ((unsigned)f2bf(v0.w) << 16);
            pk.z = (unsigned)f2bf(v1.x) | ((unsigned)f2bf(v1.y) << 16);
            pk.w = (unsigned)f2bf(v1.z) | ((unsigned)f2bf(v1.w) << 16);
        }
        *(uint4*)&xs[row][co] = pk;
    }
    __syncthreads();
    int wave = tid >> 6;
    int lane = tid & 63;
    int lrow = lane & 15;
    int kg = lane >> 4;
    int colbase = wave << 5;
    f32x4 acc[4][2][2];
    #pragma unroll
    for (int r = 0; r < 4; ++r)
        #pragma unroll
        for (int c = 0; c < 2; ++c) {
            acc[r][c][0] = (f32x4){0.f, 0.f, 0.f, 0.f};
            acc[r][c][1] = (f32x4){0.f, 0.f, 0.f, 0.f};
        }
    #pragma unroll
    for (int ks = 0; ks < 4; ++ks) {
        int kb = ks * 32 + kg * 8;
        bf16x8 af[4];
        #pragma unroll
        for (int r = 0; r < 4; ++r) af[r] = *(const bf16x8*)&xs[r * 16 + lrow][kb];
        bf16x8 bS[2], bN[2];
        #pragma unroll
        for (int c = 0; c < 2; ++c) {
            int col = colbase + c * 16 + lrow;
            bS[c] = *(const bf16x8*)(WsT + (size_t)col * 128 + kb);
            bN[c] = *(const bf16x8*)(WnT + (size_t)col * 128 + kb);
        }
        #pragma unroll
        for (int r = 0; r < 4; ++r)
            #pragma unroll
            for (int c = 0; c < 2; ++c) {
                acc[r][c][0] = __builtin_amdgcn_mfma_f32_16x16x32_bf16(af[r], bS[c], acc[r][c][0], 0, 0, 0);
                acc[r][c][1] = __builtin_amdgcn_mfma_f32_16x16x32_bf16(af[r], bN[c], acc[r][c][1], 0, 0, 0);
            }
    }
    #pragma unroll
    for (int r = 0; r < 4; ++r)
        #pragma unroll
        for (int c = 0; c < 2; ++c) {
            int col = colbase + c * 16 + lrow;
            float bv = bias[col];
            #pragma unroll
            for (int q = 0; q < 4; ++q) {
                int n = br + r * 16 + kg * 4 + q;
                if (n < N) {
                    Ab[(size_t)n * 128 + col] = f2bf(acc[r][c][0][q] + bv);
                    Tb[(size_t)n * 128 + col] = f2bf(acc[r][c][1][q]);
                }
            }
        }
}

// ---------- fused gather + GEMM (layers 1 and 2), 512 threads ----------
// Phase 1: each of 8 waves gathers 8 dst nodes (H = relu(Aprev + agg(Tprev)*dinv)) into xs.
//          LAYER2: also stage noise (fp32->bf16) into xz.
// Phase 2: MFMA. LAYER1: dual GEMM vs WsT/WnT -> Ab,Tb.  LAYER2: [Ws2|Wn2]cat over (xh,xz) -> Sb,Tb.
template <bool LAYER2>
__global__ __launch_bounds__(512) void k_fused(
    const unsigned* __restrict__ Tprev, const unsigned* __restrict__ Aprev,
    const float* __restrict__ dinv, const int* __restrict__ row_start,
    const int* __restrict__ csr, const float* __restrict__ NZ,
    const unsigned short* __restrict__ WT_s, const unsigned short* __restrict__ WT_n,
    const float* __restrict__ bias,
    unsigned short* __restrict__ OutA, unsigned short* __restrict__ OutT, int N) {
    __shared__ unsigned short xs[64][136];
    __shared__ unsigned short xz[LAYER2 ? 64 : 1][LAYER2 ? 136 : 8];
    int tid = threadIdx.x;
    int wave = tid >> 6;
    int lane = tid & 63;
    int br = blockIdx.x << 6;

    if constexpr (LAYER2) {
        #pragma unroll
        for (int it = 0; it < 2; ++it) {
            int idx = tid + it * 512;
            int row = idx >> 4;
            int co = (idx & 15) << 3;
            int n = br + row;
            uint4 pz = make_uint4(0, 0, 0, 0);
            if (n < N) {
                float4 v0 = *(const float4*)(NZ + (size_t)n * 128 + co);
                float4 v1 = *(const float4*)(NZ + (size_t)n * 128 + co + 4);
                pz.x = (unsigned)f2bf(v0.x) | ((unsigned)f2bf(v0.y) << 16);
                pz.y = (unsigned)f2bf(v0.z) | ((unsigned)f2bf(v0.w) << 16);
                pz.z = (unsigned)f2bf(v1.x) | ((unsigned)f2bf(v1.y) << 16);
                pz.w = (unsigned)f2bf(v1.z) | ((unsigned)f2bf(v1.w) << 16);
            }
            *(uint4*)&xz[row][co] = pz;
        }
    }

    // gather phase: wave handles nodes [br + wave*8, br + wave*8 + 8)
    #pragma unroll
    for (int i = 0; i < 8; ++i) {
        int trow = wave * 8 + i;
        int n = br + trow;
        unsigned pk = 0;
        if (n < N) {
            int eb = row_start[n], ee = row_start[n + 1];
            float ax = 0.f, ay = 0.f;
            int e = eb;
            for (; e + 8 <= ee; e += 8) {
                int o[8];
                #pragma unroll
                for (int j = 0; j < 8; ++j) o[j] = csr[e + j];
                unsigned v[8];
                #pragma unroll
                for (int j = 0; j < 8; ++j) v[j] = Tprev[(size_t)o[j] + lane];
                #pragma unroll
                for (int j = 0; j < 8; ++j) { ax += bf2f(v[j] & 0xffff); ay += bf2f(v[j] >> 16); }
            }
            for (; e + 2 <= ee; e += 2) {
                int o0 = csr[e], o1 = csr[e + 1];
                unsigned v0 = Tprev[(size_t)o0 + lane];
                unsigned v1 = Tprev[(size_t)o1 + lane];
                ax += bf2f(v0 & 0xffff) + bf2f(v1 & 0xffff);
                ay += bf2f(v0 >> 16) + bf2f(v1 >> 16);
            }
            if (e < ee) {
                unsigned v0 = Tprev[(size_t)csr[e] + lane];
                ax += bf2f(v0 & 0xffff);
                ay += bf2f(v0 >> 16);
            }
            float di = dinv[n];
            unsigned av = Aprev[(size_t)n * 64 + lane];
            float ox = fmaxf(bf2f(av & 0xffff) + ax * di, 0.f);
            float oy = fmaxf(bf2f(av >> 16) + ay * di, 0.f);
            pk = (unsigned)f2bf(ox) | ((unsigned)f2bf(oy) << 16);
        }
        *(unsigned*)&xs[trow][lane * 2] = pk;
    }
    __syncthreads();

    // MFMA phase: 8 waves = 2 row-halves x 4 col-groups
    int rw = wave >> 2;            // 0/1 -> rows 0-31 / 32-63
    int cw = wave & 3;             // col group of 32
    int lrow = lane & 15;
    int kg = lane >> 4;
    int colbase = cw << 5;
    f32x4 acc[2][2][2];
    #pragma unroll
    for (int r = 0; r < 2; ++r)
        #pragma unroll
        for (int c = 0; c < 2; ++c) {
            acc[r][c][0] = (f32x4){0.f, 0.f, 0.f, 0.f};
            acc[r][c][1] = (f32x4){0.f, 0.f, 0.f, 0.f};
        }
    #pragma unroll
    for (int ks = 0; ks < 4; ++ks) {
        int kb = ks * 32 + kg * 8;
        bf16x8 a0[2], a1[2];
        #pragma unroll
        for (int r = 0; r < 2; ++r) {
            a0[r] = *(const bf16x8*)&xs[rw * 32 + r * 16 + lrow][kb];
            if constexpr (LAYER2) a1[r] = *(const bf16x8*)&xz[rw * 32 + r * 16 + lrow][kb];
        }
        bf16x8 b0[2], b1[2];
        #pragma unroll
        for (int c = 0; c < 2; ++c) {
            int col = colbase + c * 16 + lrow;
            b0[c] = *(const bf16x8*)(WT_s + (size_t)col * 128 + kb);
            if constexpr (!LAYER2) b1[c] = *(const bf16x8*)(WT_n + (size_t)col * 128 + kb);
        }
        #pragma unroll
        for (int r = 0; r < 2; ++r)
            #pragma unroll
            for (int c = 0; c < 2; ++c) {
                if constexpr (LAYER2) {
                    acc[r][c][0] = __builtin_amdgcn_mfma_f32_16x16x32_bf16(a0[r], b0[c], acc[r][c][0], 0, 0, 0);
                    acc[r][c][1] = __builtin_amdgcn_mfma_f32_16x16x32_bf16(a1[r], b0[c], acc[r][c][1], 0, 0, 0);
                } else {
                    acc[r][c][0] = __builtin_amdgcn_mfma_f32_16x16x32_bf16(a0[r], b0[c], acc[r][c][0], 0, 0, 0);
                    acc[r][c][1] = __builtin_amdgcn_mfma_f32_16x16x32_bf16(a0[r], b1[c], acc[r][c][1], 0, 0, 0);
                }
            }
    }
    if constexpr (!LAYER2) {
        #pragma unroll
        for (int r = 0; r < 2; ++r)
            #pragma unroll
            for (int c = 0; c < 2; ++c) {
                int col = colbase + c * 16 + lrow;
                float bv = bias[col];
                #pragma unroll
                for (int q = 0; q < 4; ++q) {
                    int n = br + rw * 32 + r * 16 + kg * 4 + q;
                    if (n < N) {
                        OutA[(size_t)n * 128 + col] = f2bf(acc[r][c][0][q] + bv);
                        OutT[(size_t)n * 128 + col] = f2bf(acc[r][c][1][q]);
                    }
                }
            }
    } else {
        if (cw < 2) {
            #pragma unroll
            for (int r = 0; r < 2; ++r)
                #pragma unroll
                for (int c = 0; c < 2; ++c) {
                    int j = colbase + c * 16 + lrow;
                    float bv = bias[j];
                    #pragma unroll
                    for (int q = 0; q < 4; ++q) {
                        int n = br + rw * 32 + r * 16 + kg * 4 + q;
                        if (n < N) {
                            float hs = acc[r][c][0][q] + bv;
                            float zs = acc[r][c][1][q];
                            unsigned pk = (unsigned)f2bf(hs) | ((unsigned)f2bf(hs + zs) << 16);
                            ((unsigned*)OutA)[(size_t)n * 64 + j] = pk;
                        }
                    }
                }
        } else {
            #pragma unroll
            for (int r = 0; r < 2; ++r)
                #pragma unroll
                for (int c = 0; c < 2; ++c) {
                    int j = colbase - 64 + c * 16 + lrow;
                    #pragma unroll
                    for (int q = 0; q < 4; ++q) {
                        int n = br + rw * 32 + r * 16 + kg * 4 + q;
                        if (n < N) {
                            unsigned pk = (unsigned)f2bf(acc[r][c][0][q]) |
                                          ((unsigned)f2bf(acc[r][c][1][q]) << 16);
                            ((unsigned*)OutT)[(size_t)n * 64 + j] = pk;
                        }
                    }
                }
        }
    }
}

// ---------- layer-2 aggregation: out = self + agg (batch-16 gathers) ----------
__global__ __launch_bounds__(256) void k_agg_final2(
    const unsigned short* __restrict__ Tb, const unsigned short* __restrict__ Sb,
    const float* __restrict__ dinv, const int* __restrict__ row_start,
    const int* __restrict__ csr, float* __restrict__ out, int N) {
    int w = (blockIdx.x * 256 + threadIdx.x) >> 6;
    int lane = threadIdx.x & 63;
    if (w >= N) return;
    int eb = row_start[w], ee = row_start[w + 1];
    const unsigned* Tv = (const unsigned*)Tb;
    float ax = 0.f, ay = 0.f;
    int e = eb;
    for (; e + 16 <= ee; e += 16) {
        int o[16];
        #pragma unroll
        for (int j = 0; j < 16; ++j) o[j] = csr[e + j];
        unsigned v[16];
        #pragma unroll
        for (int j = 0; j < 16; ++j) v[j] = Tv[(size_t)o[j] + lane];
        #pragma unroll
        for (int j = 0; j < 16; ++j) { ax += bf2f(v[j] & 0xffff); ay += bf2f(v[j] >> 16); }
    }
    for (; e + 4 <= ee; e += 4) {
        int o[4];
        #pragma unroll
        for (int j = 0; j < 4; ++j) o[j] = csr[e + j];
        unsigned v[4];
        #pragma unroll
        for (int j = 0; j < 4; ++j) v[j] = Tv[(size_t)o[j] + lane];
        #pragma unroll
        for (int j = 0; j < 4; ++j) { ax += bf2f(v[j] & 0xffff); ay += bf2f(v[j] >> 16); }
    }
    for (; e < ee; ++e) {
        unsigned v0 = Tv[(size_t)csr[e] + lane];
        ax += bf2f(v0 & 0xffff);
        ay += bf2f(v0 >> 16);
    }
    float di = dinv[w];
    unsigned sv = ((const unsigned*)Sb)[(size_t)w * 64 + lane];
    float* orow = out + (size_t)w * 128;
    orow[64 + lane] = bf2f(sv & 0xffff) + ax * di;
    orow[lane]      = bf2f(sv >> 16) + (ax + ay) * di;
}

extern "C" void kernel_launch(void* const* d_in, const int* in_sizes, int n_in,
                              void* d_out, int out_size, void* d_ws, size_t ws_size,
                              hipStream_t stream) {
    const float* features = (const float*)d_in[0];
    const float* noise    = (const float*)d_in[1];
    const float* Ws0 = (const float*)d_in[2];
    const float* Wn0 = (const float*)d_in[3];
    const float* b0  = (const float*)d_in[4];
    const float* Ws1 = (const float*)d_in[5];
    const float* Wn1 = (const float*)d_in[6];
    const float* b1  = (const float*)d_in[7];
    const float* Ws2 = (const float*)d_in[8];
    const float* Wn2 = (const float*)d_in[9];
    const float* b2  = (const float*)d_in[10];
    const int* esrc = (const int*)d_in[11];
    const int* edst = (const int*)d_in[12];
    int N = in_sizes[0] / 128;
    int E = in_sizes[11];
    float* out = (float*)d_out;

    // workspace
    unsigned short* Ab0 = (unsigned short*)d_ws;
    unsigned short* Tb0 = Ab0 + (size_t)N * 128;
    unsigned short* Ab1 = Tb0 + (size_t)N * 128;
    unsigned short* Tb1 = Ab1 + (size_t)N * 128;
    unsigned short* Sb  = Tb1 + (size_t)N * 128;
    unsigned short* Tb2 = Sb  + (size_t)N * 128;
    unsigned short* WT0s = Tb2 + (size_t)N * 128;
    unsigned short* WT0n = WT0s + 128 * 128;
    unsigned short* WT1s = WT0n + 128 * 128;
    unsigned short* WT1n = WT1s + 128 * 128;
    unsigned short* WT2  = WT1n + 128 * 128;
    float* dinv = (float*)(WT2 + 128 * 128);
    int* row_start = (int*)(dinv + N);
    int* csr       = row_start + (N + 1);
    unsigned* bsorted = (unsigned*)(csr + E);
    int* bcount  = (int*)(bsorted + E);
    int* bbase   = bcount + 256;
    int* bcursor = bbase + 257;

    int nbk = (N + 255) >> 8;
    int ech = (E + CHUNK - 1) / CHUNK;

    hipMemsetAsync(bcount, 0, 256 * sizeof(int), stream);
    k_bucket_count<<<ech, 256, 0, stream>>>(edst, bcount, E);
    k_bucket_scan<<<1, 256, 0, stream>>>(bcount, bbase, bcursor, E);
    k_bucket_scatter<<<ech, 256, 0, stream>>>(esrc, edst, bcursor, bsorted, E);
    k_bucket_csr<<<nbk, 256, 0, stream>>>(bsorted, bbase, row_start, dinv, csr, N, E);

    k_wT_all<<<320, 256, 0, stream>>>(Ws0, Wn0, Ws1, Wn1, Ws2, Wn2,
                                      WT0s, WT0n, WT1s, WT1n, WT2);

    int g64 = (N + 63) / 64;

    // layer 0 GEMM
    k_mfma_dual0<<<g64, 256, 0, stream>>>(features, WT0s, WT0n, b0, Ab0, Tb0, N);
    // fused agg0 + layer-1 GEMM
    k_fused<false><<<g64, 512, 0, stream>>>((const unsigned*)Tb0, (const unsigned*)Ab0,
                                            dinv, row_start, csr, nullptr,
                                            WT1s, WT1n, b1, Ab1, Tb1, N);
    // fused agg1 + layer-2 GEMM (noise staged alongside)
    k_fused<true><<<g64, 512, 0, stream>>>((const unsigned*)Tb1, (const unsigned*)Ab1,
                                           dinv, row_start, csr, noise,
                                           WT2, nullptr, b2, Sb, Tb2, N);
    // final aggregation -> out
    int ablocks = (N * 64 + 255) / 256;
    k_agg_final2<<<ablocks, 256, 0, stream>>>(Tb2, Sb, dinv, row_start, csr, out, N);
}

// Round 10
// 213.967 us; speedup vs baseline: 1.2043x; 1.2043x over previous
//
#include <hip/hip_runtime.h>

typedef __attribute__((ext_vector_type(8))) short bf16x8;
typedef __attribute__((ext_vector_type(4))) float f32x4;

__device__ __forceinline__ unsigned short f2bf(float x) {
    union { float f; unsigned u; } v; v.f = x;
    unsigned r = v.u + 0x7FFFu + ((v.u >> 16) & 1u);
    return (unsigned short)(r >> 16);
}
__device__ __forceinline__ float bf2f(unsigned u) {
    union { unsigned u; float f; } v; v.u = u << 16;
    return v.f;
}

#define CHUNK 4096

// ---------- K1: bucket count (blocks < ech) UNION weight transpose (blocks >= ech) ----------
__global__ __launch_bounds__(256) void k_count_wt(
    const int* __restrict__ edst, int* __restrict__ bcount, int E, int ech,
    const float* __restrict__ Ws0, const float* __restrict__ Wn0,
    const float* __restrict__ Ws1, const float* __restrict__ Wn1,
    const float* __restrict__ Ws2, const float* __restrict__ Wn2,
    unsigned short* __restrict__ WT0s, unsigned short* __restrict__ WT0n,
    unsigned short* __restrict__ WT1s, unsigned short* __restrict__ WT1n,
    unsigned short* __restrict__ WT2) {
    __shared__ int hist[256];
    int tid = threadIdx.x;
    if ((int)blockIdx.x < ech) {
        hist[tid] = 0;
        __syncthreads();
        int e0 = blockIdx.x * CHUNK;
        int cnt = min(CHUNK, E - e0);
        for (int i = tid; i < cnt; i += 256) atomicAdd(&hist[edst[e0 + i] >> 8], 1);
        __syncthreads();
        if (hist[tid]) atomicAdd(&bcount[tid], hist[tid]);
    } else {
        int i = (blockIdx.x - ech) * 256 + tid;
        if (i < 16384)      { int j = i;         WT0s[j] = f2bf(Ws0[(j & 127) * 128 + (j >> 7)]); }
        else if (i < 32768) { int j = i - 16384; WT0n[j] = f2bf(Wn0[(j & 127) * 128 + (j >> 7)]); }
        else if (i < 49152) { int j = i - 32768; WT1s[j] = f2bf(Ws1[(j & 127) * 128 + (j >> 7)]); }
        else if (i < 65536) { int j = i - 49152; WT1n[j] = f2bf(Wn1[(j & 127) * 128 + (j >> 7)]); }
        else if (i < 73728) { int j = i - 65536; WT2[j] = f2bf(Ws2[(j & 127) * 64 + (j >> 7)]); }
        else if (i < 81920) { int j = i - 73728; WT2[8192 + j] = f2bf(Wn2[(j & 127) * 64 + (j >> 7)]); }
    }
}

// ---------- K2: scan of bucket counts ----------
__global__ __launch_bounds__(256) void k_bucket_scan(const int* __restrict__ bcount,
                                                     int* __restrict__ bbase,
                                                     int* __restrict__ bcursor, int E) {
    __shared__ int sh[256];
    int tid = threadIdx.x;
    int v = bcount[tid];
    sh[tid] = v;
    __syncthreads();
    for (int off = 1; off < 256; off <<= 1) {
        int t = (tid >= off) ? sh[tid - off] : 0;
        __syncthreads();
        sh[tid] += t;
        __syncthreads();
    }
    int excl = sh[tid] - v;
    bbase[tid] = excl;
    bcursor[tid] = excl;
    if (tid == 0) bbase[256] = E;
}

// ---------- K3: layer-0 MFMA GEMM (blocks < g64) UNION bucket scatter (blocks >= g64) ----------
__global__ __launch_bounds__(256) void k_gemm0_scatter(
    const float* __restrict__ Xf,
    const unsigned short* __restrict__ WsT, const unsigned short* __restrict__ WnT,
    const float* __restrict__ bias, unsigned short* __restrict__ Ab,
    unsigned short* __restrict__ Tb, int N, int g64,
    const int* __restrict__ esrc, const int* __restrict__ edst,
    int* __restrict__ bcursor, unsigned* __restrict__ bsorted, int E) {
    __shared__ uint4 smem[1216];   // 19456 B, union of both branches
    int tid = threadIdx.x;
    if ((int)blockIdx.x < g64) {
        // ---- layer-0 dual GEMM from fp32 features ----
        unsigned short (*xs)[136] = (unsigned short(*)[136])smem;
        int br = blockIdx.x << 6;
        #pragma unroll
        for (int it = 0; it < 4; ++it) {
            int idx = tid + it * 256;
            int row = idx >> 4;
            int co = (idx & 15) << 3;
            int n = br + row;
            uint4 pk = make_uint4(0, 0, 0, 0);
            if (n < N) {
                float4 v0 = *(const float4*)(Xf + (size_t)n * 128 + co);
                float4 v1 = *(const float4*)(Xf + (size_t)n * 128 + co + 4);
                pk.x = (unsigned)f2bf(v0.x) | ((unsigned)f2bf(v0.y) << 16);
                pk.y = (unsigned)f2bf(v0.z) | ((unsigned)f2bf(v0.w) << 16);
                pk.z = (unsigned)f2bf(v1.x) | ((unsigned)f2bf(v1.y) << 16);
                pk.w = (unsigned)f2bf(v1.z) | ((unsigned)f2bf(v1.w) << 16);
            }
            *(uint4*)&xs[row][co] = pk;
        }
        __syncthreads();
        int wave = tid >> 6;
        int lane = tid & 63;
        int lrow = lane & 15;
        int kg = lane >> 4;
        int colbase = wave << 5;
        f32x4 acc[4][2][2];
        #pragma unroll
        for (int r = 0; r < 4; ++r)
            #pragma unroll
            for (int c = 0; c < 2; ++c) {
                acc[r][c][0] = (f32x4){0.f, 0.f, 0.f, 0.f};
                acc[r][c][1] = (f32x4){0.f, 0.f, 0.f, 0.f};
            }
        #pragma unroll
        for (int ks = 0; ks < 4; ++ks) {
            int kb = ks * 32 + kg * 8;
            bf16x8 af[4];
            #pragma unroll
            for (int r = 0; r < 4; ++r) af[r] = *(const bf16x8*)&xs[r * 16 + lrow][kb];
            bf16x8 bS[2], bN[2];
            #pragma unroll
            for (int c = 0; c < 2; ++c) {
                int col = colbase + c * 16 + lrow;
                bS[c] = *(const bf16x8*)(WsT + (size_t)col * 128 + kb);
                bN[c] = *(const bf16x8*)(WnT + (size_t)col * 128 + kb);
            }
            #pragma unroll
            for (int r = 0; r < 4; ++r)
                #pragma unroll
                for (int c = 0; c < 2; ++c) {
                    acc[r][c][0] = __builtin_amdgcn_mfma_f32_16x16x32_bf16(af[r], bS[c], acc[r][c][0], 0, 0, 0);
                    acc[r][c][1] = __builtin_amdgcn_mfma_f32_16x16x32_bf16(af[r], bN[c], acc[r][c][1], 0, 0, 0);
                }
        }
        #pragma unroll
        for (int r = 0; r < 4; ++r)
            #pragma unroll
            for (int c = 0; c < 2; ++c) {
                int col = colbase + c * 16 + lrow;
                float bv = bias[col];
                #pragma unroll
                for (int q = 0; q < 4; ++q) {
                    int n = br + r * 16 + kg * 4 + q;
                    if (n < N) {
                        Ab[(size_t)n * 128 + col] = f2bf(acc[r][c][0][q] + bv);
                        Tb[(size_t)n * 128 + col] = f2bf(acc[r][c][1][q]);
                    }
                }
            }
    } else {
        // ---- bucket scatter ----
        unsigned* stage = (unsigned*)smem;           // [4096]
        int* hist = (int*)(stage + CHUNK);           // [256]
        int* base = hist + 256;                      // [256]
        int* cur  = base + 256;                      // [256]
        hist[tid] = 0;
        __syncthreads();
        int e0 = (blockIdx.x - g64) * CHUNK;
        int cnt = min(CHUNK, E - e0);
        for (int i = tid; i < cnt; i += 256) {
            int d = edst[e0 + i], s = esrc[e0 + i];
            stage[i] = ((unsigned)d << 16) | (unsigned)s;
            atomicAdd(&hist[d >> 8], 1);
        }
        __syncthreads();
        base[tid] = hist[tid] ? atomicAdd(&bcursor[tid], hist[tid]) : 0;
        cur[tid] = 0;
        __syncthreads();
        for (int i = tid; i < cnt; i += 256) {
            unsigned pk = stage[i];
            int b = pk >> 24;
            int p = base[b] + atomicAdd(&cur[b], 1);
            bsorted[p] = pk;
        }
    }
}

// ---------- K4: per-bucket CSR finalize; csr stores PRE-SCALED uint offsets (src<<6) ----------
__global__ __launch_bounds__(256) void k_bucket_csr(const unsigned* __restrict__ bsorted,
                                                    const int* __restrict__ bbase,
                                                    int* __restrict__ row_start,
                                                    float* __restrict__ dinv,
                                                    int* __restrict__ csr, int N, int E) {
    __shared__ int sh[256];
    __shared__ int cur[256];
    int tid = threadIdx.x;
    int b = blockIdx.x;
    int lo = bbase[b], hi = bbase[b + 1];
    sh[tid] = 0;
    __syncthreads();
    for (int i = lo + tid; i < hi; i += 256) atomicAdd(&sh[(bsorted[i] >> 16) & 255], 1);
    __syncthreads();
    int v = sh[tid];
    __syncthreads();
    sh[tid] = v;
    __syncthreads();
    for (int off = 1; off < 256; off <<= 1) {
        int t = (tid >= off) ? sh[tid - off] : 0;
        __syncthreads();
        sh[tid] += t;
        __syncthreads();
    }
    int excl = sh[tid] - v;
    int d = (b << 8) + tid;
    if (d < N) {
        row_start[d] = lo + excl;
        dinv[d] = 1.0f / (float)(v > 1 ? v : 1);
    }
    cur[tid] = lo + excl;
    __syncthreads();
    for (int i = lo + tid; i < hi; i += 256) {
        unsigned pk = bsorted[i];
        int p = atomicAdd(&cur[(pk >> 16) & 255], 1);
        csr[p] = (int)(pk & 0xffffu) << 6;
    }
    if (b == 0 && tid == 0) row_start[N] = E;
}

// ---------- MFMA dual GEMM, bf16 input: Ab = bf16(X@Ws + b), Tb = bf16(X@Wn) ----------
__global__ __launch_bounds__(256) void k_mfma_dual(
    const unsigned short* __restrict__ Xin,
    const unsigned short* __restrict__ WsT, const unsigned short* __restrict__ WnT,
    const float* __restrict__ bias, unsigned short* __restrict__ Ab,
    unsigned short* __restrict__ Tb, int N) {
    __shared__ unsigned short xs[64][136];
    int tid = threadIdx.x;
    int br = blockIdx.x << 6;
    #pragma unroll
    for (int it = 0; it < 4; ++it) {
        int idx = tid + it * 256;
        int row = idx >> 4;
        int co = (idx & 15) << 3;
        int n = br + row;
        uint4 pk = make_uint4(0, 0, 0, 0);
        if (n < N) pk = *(const uint4*)(Xin + (size_t)n * 128 + co);
        *(uint4*)&xs[row][co] = pk;
    }
    __syncthreads();
    int wave = tid >> 6;
    int lane = tid & 63;
    int lrow = lane & 15;
    int kg = lane >> 4;
    int colbase = wave << 5;
    f32x4 acc[4][2][2];
    #pragma unroll
    for (int r = 0; r < 4; ++r)
        #pragma unroll
        for (int c = 0; c < 2; ++c) {
            acc[r][c][0] = (f32x4){0.f, 0.f, 0.f, 0.f};
            acc[r][c][1] = (f32x4){0.f, 0.f, 0.f, 0.f};
        }
    #pragma unroll
    for (int ks = 0; ks < 4; ++ks) {
        int kb = ks * 32 + kg * 8;
        bf16x8 af[4];
        #pragma unroll
        for (int r = 0; r < 4; ++r) af[r] = *(const bf16x8*)&xs[r * 16 + lrow][kb];
        bf16x8 bS[2], bN[2];
        #pragma unroll
        for (int c = 0; c < 2; ++c) {
            int col = colbase + c * 16 + lrow;
            bS[c] = *(const bf16x8*)(WsT + (size_t)col * 128 + kb);
            bN[c] = *(const bf16x8*)(WnT + (size_t)col * 128 + kb);
        }
        #pragma unroll
        for (int r = 0; r < 4; ++r)
            #pragma unroll
            for (int c = 0; c < 2; ++c) {
                acc[r][c][0] = __builtin_amdgcn_mfma_f32_16x16x32_bf16(af[r], bS[c], acc[r][c][0], 0, 0, 0);
                acc[r][c][1] = __builtin_amdgcn_mfma_f32_16x16x32_bf16(af[r], bN[c], acc[r][c][1], 0, 0, 0);
            }
    }
    #pragma unroll
    for (int r = 0; r < 4; ++r)
        #pragma unroll
        for (int c = 0; c < 2; ++c) {
            int col = colbase + c * 16 + lrow;
            float bv = bias[col];
            #pragma unroll
            for (int q = 0; q < 4; ++q) {
                int n = br + r * 16 + kg * 4 + q;
                if (n < N) {
                    Ab[(size_t)n * 128 + col] = f2bf(acc[r][c][0][q] + bv);
                    Tb[(size_t)n * 128 + col] = f2bf(acc[r][c][1][q]);
                }
            }
        }
}

// ---------- aggregation layers 0/1: Hb = bf16(relu(Ab + agg(Tb)*dinv)), batch-16 ----------
__global__ __launch_bounds__(256) void k_agg_relu_bf16(
    const unsigned* __restrict__ Tv, const unsigned* __restrict__ Av,
    const float* __restrict__ dinv, const int* __restrict__ row_start,
    const int* __restrict__ csr, unsigned* __restrict__ Hv, int N) {
    int w = (blockIdx.x * 256 + threadIdx.x) >> 6;
    int lane = threadIdx.x & 63;
    if (w >= N) return;
    int eb = row_start[w], ee = row_start[w + 1];
    float ax = 0.f, ay = 0.f;
    int e = eb;
    for (; e + 16 <= ee; e += 16) {
        int o[16];
        #pragma unroll
        for (int j = 0; j < 16; ++j) o[j] = csr[e + j];
        unsigned v[16];
        #pragma unroll
        for (int j = 0; j < 16; ++j) v[j] = Tv[(size_t)o[j] + lane];
        #pragma unroll
        for (int j = 0; j < 16; ++j) { ax += bf2f(v[j] & 0xffff); ay += bf2f(v[j] >> 16); }
    }
    for (; e + 4 <= ee; e += 4) {
        int o[4];
        #pragma unroll
        for (int j = 0; j < 4; ++j) o[j] = csr[e + j];
        unsigned v[4];
        #pragma unroll
        for (int j = 0; j < 4; ++j) v[j] = Tv[(size_t)o[j] + lane];
        #pragma unroll
        for (int j = 0; j < 4; ++j) { ax += bf2f(v[j] & 0xffff); ay += bf2f(v[j] >> 16); }
    }
    for (; e < ee; ++e) {
        unsigned v0 = Tv[(size_t)csr[e] + lane];
        ax += bf2f(v0 & 0xffff);
        ay += bf2f(v0 >> 16);
    }
    float di = dinv[w];
    unsigned av = Av[(size_t)w * 64 + lane];
    float ox = fmaxf(bf2f(av & 0xffff) + ax * di, 0.f);
    float oy = fmaxf(bf2f(av >> 16) + ay * di, 0.f);
    Hv[(size_t)w * 64 + lane] = (unsigned)f2bf(ox) | ((unsigned)f2bf(oy) << 16);
}

// ---------- layer-2 MFMA: self sums -> Sb (packed bf16), neighbor transforms -> Tb ----------
__global__ __launch_bounds__(256) void k_mfma_layer2(
    const unsigned short* __restrict__ Hb, const float* __restrict__ NZ,
    const unsigned short* __restrict__ WTcat, const float* __restrict__ b2,
    unsigned short* __restrict__ Sb, unsigned short* __restrict__ Tb, int N) {
    __shared__ unsigned short xh[64][136];
    __shared__ unsigned short xz[64][136];
    int tid = threadIdx.x;
    int br = blockIdx.x << 6;
    #pragma unroll
    for (int it = 0; it < 4; ++it) {
        int idx = tid + it * 256;
        int row = idx >> 4;
        int co = (idx & 15) << 3;
        int n = br + row;
        uint4 ph = make_uint4(0, 0, 0, 0), pz = make_uint4(0, 0, 0, 0);
        if (n < N) {
            ph = *(const uint4*)(Hb + (size_t)n * 128 + co);
            float4 v0 = *(const float4*)(NZ + (size_t)n * 128 + co);
            float4 v1 = *(const float4*)(NZ + (size_t)n * 128 + co + 4);
            pz.x = (unsigned)f2bf(v0.x) | ((unsigned)f2bf(v0.y) << 16);
            pz.y = (unsigned)f2bf(v0.z) | ((unsigned)f2bf(v0.w) << 16);
            pz.z = (unsigned)f2bf(v1.x) | ((unsigned)f2bf(v1.y) << 16);
            pz.w = (unsigned)f2bf(v1.z) | ((unsigned)f2bf(v1.w) << 16);
        }
        *(uint4*)&xh[row][co] = ph;
        *(uint4*)&xz[row][co] = pz;
    }
    __syncthreads();
    int wave = tid >> 6;
    int lane = tid & 63;
    int lrow = lane & 15;
    int kg = lane >> 4;
    int colbase = wave << 5;
    f32x4 acc[4][2][2];
    #pragma unroll
    for (int r = 0; r < 4; ++r)
        #pragma unroll
        for (int c = 0; c < 2; ++c) {
            acc[r][c][0] = (f32x4){0.f, 0.f, 0.f, 0.f};
            acc[r][c][1] = (f32x4){0.f, 0.f, 0.f, 0.f};
        }
    #pragma unroll
    for (int ks = 0; ks < 4; ++ks) {
        int kb = ks * 32 + kg * 8;
        bf16x8 ah[4], az[4];
        #pragma unroll
        for (int r = 0; r < 4; ++r) {
            ah[r] = *(const bf16x8*)&xh[r * 16 + lrow][kb];
            az[r] = *(const bf16x8*)&xz[r * 16 + lrow][kb];
        }
        bf16x8 bw[2];
        #pragma unroll
        for (int c = 0; c < 2; ++c) {
            int col = colbase + c * 16 + lrow;
            bw[c] = *(const bf16x8*)(WTcat + (size_t)col * 128 + kb);
        }
        #pragma unroll
        for (int r = 0; r < 4; ++r)
            #pragma unroll
            for (int c = 0; c < 2; ++c) {
                acc[r][c][0] = __builtin_amdgcn_mfma_f32_16x16x32_bf16(ah[r], bw[c], acc[r][c][0], 0, 0, 0);
                acc[r][c][1] = __builtin_amdgcn_mfma_f32_16x16x32_bf16(az[r], bw[c], acc[r][c][1], 0, 0, 0);
            }
    }
    if (wave < 2) {
        #pragma unroll
        for (int r = 0; r < 4; ++r)
            #pragma unroll
            for (int c = 0; c < 2; ++c) {
                int j = colbase + c * 16 + lrow;
                float bv = b2[j];
                #pragma unroll
                for (int q = 0; q < 4; ++q) {
                    int n = br + r * 16 + kg * 4 + q;
                    if (n < N) {
                        float hs = acc[r][c][0][q] + bv;
                        float zs = acc[r][c][1][q];
                        unsigned pk = (unsigned)f2bf(hs) | ((unsigned)f2bf(hs + zs) << 16);
                        ((unsigned*)Sb)[(size_t)n * 64 + j] = pk;
                    }
                }
            }
    } else {
        #pragma unroll
        for (int r = 0; r < 4; ++r)
            #pragma unroll
            for (int c = 0; c < 2; ++c) {
                int j = colbase - 64 + c * 16 + lrow;
                #pragma unroll
                for (int q = 0; q < 4; ++q) {
                    int n = br + r * 16 + kg * 4 + q;
                    if (n < N) {
                        unsigned pk = (unsigned)f2bf(acc[r][c][0][q]) |
                                      ((unsigned)f2bf(acc[r][c][1][q]) << 16);
                        ((unsigned*)Tb)[(size_t)n * 64 + j] = pk;
                    }
                }
            }
    }
}

// ---------- layer-2 aggregation: out = self + agg (batch-16) ----------
__global__ __launch_bounds__(256) void k_agg_final2(
    const unsigned short* __restrict__ Tb, const unsigned short* __restrict__ Sb,
    const float* __restrict__ dinv, const int* __restrict__ row_start,
    const int* __restrict__ csr, float* __restrict__ out, int N) {
    int w = (blockIdx.x * 256 + threadIdx.x) >> 6;
    int lane = threadIdx.x & 63;
    if (w >= N) return;
    int eb = row_start[w], ee = row_start[w + 1];
    const unsigned* Tv = (const unsigned*)Tb;
    float ax = 0.f, ay = 0.f;
    int e = eb;
    for (; e + 16 <= ee; e += 16) {
        int o[16];
        #pragma unroll
        for (int j = 0; j < 16; ++j) o[j] = csr[e + j];
        unsigned v[16];
        #pragma unroll
        for (int j = 0; j < 16; ++j) v[j] = Tv[(size_t)o[j] + lane];
        #pragma unroll
        for (int j = 0; j < 16; ++j) { ax += bf2f(v[j] & 0xffff); ay += bf2f(v[j] >> 16); }
    }
    for (; e + 4 <= ee; e += 4) {
        int o[4];
        #pragma unroll
        for (int j = 0; j < 4; ++j) o[j] = csr[e + j];
        unsigned v[4];
        #pragma unroll
        for (int j = 0; j < 4; ++j) v[j] = Tv[(size_t)o[j] + lane];
        #pragma unroll
        for (int j = 0; j < 4; ++j) { ax += bf2f(v[j] & 0xffff); ay += bf2f(v[j] >> 16); }
    }
    for (; e < ee; ++e) {
        unsigned v0 = Tv[(size_t)csr[e] + lane];
        ax += bf2f(v0 & 0xffff);
        ay += bf2f(v0 >> 16);
    }
    float di = dinv[w];
    unsigned sv = ((const unsigned*)Sb)[(size_t)w * 64 + lane];
    float* orow = out + (size_t)w * 128;
    orow[64 + lane] = bf2f(sv & 0xffff) + ax * di;
    orow[lane]      = bf2f(sv >> 16) + (ax + ay) * di;
}

extern "C" void kernel_launch(void* const* d_in, const int* in_sizes, int n_in,
                              void* d_out, int out_size, void* d_ws, size_t ws_size,
                              hipStream_t stream) {
    const float* features = (const float*)d_in[0];
    const float* noise    = (const float*)d_in[1];
    const float* Ws0 = (const float*)d_in[2];
    const float* Wn0 = (const float*)d_in[3];
    const float* b0  = (const float*)d_in[4];
    const float* Ws1 = (const float*)d_in[5];
    const float* Wn1 = (const float*)d_in[6];
    const float* b1  = (const float*)d_in[7];
    const float* Ws2 = (const float*)d_in[8];
    const float* Wn2 = (const float*)d_in[9];
    const float* b2  = (const float*)d_in[10];
    const int* esrc = (const int*)d_in[11];
    const int* edst = (const int*)d_in[12];
    int N = in_sizes[0] / 128;
    int E = in_sizes[11];
    float* out = (float*)d_out;

    // workspace
    unsigned short* Ab = (unsigned short*)d_ws;            // [N][128] bf16
    unsigned short* Tb = Ab + (size_t)N * 128;             // [N][128] bf16
    unsigned short* Hb = Tb + (size_t)N * 128;             // [N][128] bf16
    unsigned short* Sb = Hb + (size_t)N * 128;             // [N][128] bf16 (pairs)
    unsigned short* WT0s = Sb + (size_t)N * 128;
    unsigned short* WT0n = WT0s + 128 * 128;
    unsigned short* WT1s = WT0n + 128 * 128;
    unsigned short* WT1n = WT1s + 128 * 128;
    unsigned short* WT2  = WT1n + 128 * 128;
    float* dinv = (float*)(WT2 + 128 * 128);
    int* row_start = (int*)(dinv + N);          // [N+1]
    int* csr       = row_start + (N + 1);       // [E]
    unsigned* bsorted = (unsigned*)(csr + E);   // [E]
    int* bcount  = (int*)(bsorted + E);         // [256]
    int* bbase   = bcount + 256;                // [257]
    int* bcursor = bbase + 257;                 // [256]

    int nbk = (N + 255) >> 8;
    int ech = (E + CHUNK - 1) / CHUNK;
    int g64 = (N + 63) / 64;

    hipMemsetAsync(bcount, 0, 256 * sizeof(int), stream);
    // K1: bucket count || weight transpose
    k_count_wt<<<ech + 320, 256, 0, stream>>>(edst, bcount, E, ech,
                                              Ws0, Wn0, Ws1, Wn1, Ws2, Wn2,
                                              WT0s, WT0n, WT1s, WT1n, WT2);
    // K2: scan
    k_bucket_scan<<<1, 256, 0, stream>>>(bcount, bbase, bcursor, E);
    // K3: layer-0 GEMM || bucket scatter
    k_gemm0_scatter<<<g64 + ech, 256, 0, stream>>>(features, WT0s, WT0n, b0, Ab, Tb, N, g64,
                                                   esrc, edst, bcursor, bsorted, E);
    // K4: per-bucket CSR finalize
    k_bucket_csr<<<nbk, 256, 0, stream>>>(bsorted, bbase, row_start, dinv, csr, N, E);

    int ablocks = (N * 64 + 255) / 256;

    k_agg_relu_bf16<<<ablocks, 256, 0, stream>>>((const unsigned*)Tb, (const unsigned*)Ab,
                                                 dinv, row_start, csr, (unsigned*)Hb, N);
    k_mfma_dual<<<g64, 256, 0, stream>>>(Hb, WT1s, WT1n, b1, Ab, Tb, N);
    k_agg_relu_bf16<<<ablocks, 256, 0, stream>>>((const unsigned*)Tb, (const unsigned*)Ab,
                                                 dinv, row_start, csr, (unsigned*)Hb, N);
    k_mfma_layer2<<<g64, 256, 0, stream>>>(Hb, noise, WT2, b2, Sb, Tb, N);
    k_agg_final2<<<ablocks, 256, 0, stream>>>(Tb, Sb, dinv, row_start, csr, out, N);
}

// Round 11
// 193.954 us; speedup vs baseline: 1.3286x; 1.1032x over previous
//
#include <hip/hip_runtime.h>

typedef __attribute__((ext_vector_type(8))) short bf16x8;
typedef __attribute__((ext_vector_type(4))) float f32x4;

__device__ __forceinline__ unsigned short f2bf(float x) {
    union { float f; unsigned u; } v; v.f = x;
    unsigned r = v.u + 0x7FFFu + ((v.u >> 16) & 1u);
    return (unsigned short)(r >> 16);
}
__device__ __forceinline__ float bf2f(unsigned u) {
    union { unsigned u; float f; } v; v.u = u << 16;
    return v.f;
}

#define CHUNK 4096
#define CAP 4608

// ---------- K1: weight transpose + zero bcursor ----------
__global__ __launch_bounds__(256) void k_wt(
    const float* __restrict__ Ws0, const float* __restrict__ Wn0,
    const float* __restrict__ Ws1, const float* __restrict__ Wn1,
    const float* __restrict__ Ws2, const float* __restrict__ Wn2,
    unsigned short* __restrict__ WT0s, unsigned short* __restrict__ WT0n,
    unsigned short* __restrict__ WT1s, unsigned short* __restrict__ WT1n,
    unsigned short* __restrict__ WT2, int* __restrict__ bcursor) {
    int tid = threadIdx.x;
    if (blockIdx.x == 0) bcursor[tid] = 0;
    int i = blockIdx.x * 256 + tid;
    if (i < 16384)      { int j = i;         WT0s[j] = f2bf(Ws0[(j & 127) * 128 + (j >> 7)]); }
    else if (i < 32768) { int j = i - 16384; WT0n[j] = f2bf(Wn0[(j & 127) * 128 + (j >> 7)]); }
    else if (i < 49152) { int j = i - 32768; WT1s[j] = f2bf(Ws1[(j & 127) * 128 + (j >> 7)]); }
    else if (i < 65536) { int j = i - 49152; WT1n[j] = f2bf(Wn1[(j & 127) * 128 + (j >> 7)]); }
    else if (i < 73728) { int j = i - 65536; WT2[j] = f2bf(Ws2[(j & 127) * 64 + (j >> 7)]); }
    else if (i < 81920) { int j = i - 73728; WT2[8192 + j] = f2bf(Wn2[(j & 127) * 64 + (j >> 7)]); }
}

// ---------- K2: bucket scatter (blocks < ech, runs first) UNION layer-0 GEMM ----------
__global__ __launch_bounds__(256) void k_scatter_gemm0(
    const int* __restrict__ esrc, const int* __restrict__ edst,
    int* __restrict__ bcursor, unsigned* __restrict__ bsorted, int E, int ech,
    const float* __restrict__ Xf,
    const unsigned short* __restrict__ WsT, const unsigned short* __restrict__ WnT,
    const float* __restrict__ bias, unsigned short* __restrict__ Ab,
    unsigned short* __restrict__ Tb, int N) {
    __shared__ uint4 smem[1216];   // 19456 B union
    int tid = threadIdx.x;
    if ((int)blockIdx.x < ech) {
        // ---- bucket scatter ----
        unsigned* stage = (unsigned*)smem;       // [4096]
        int* hist = (int*)(stage + CHUNK);       // [256]
        int* base = hist + 256;                  // [256]
        int* cur  = base + 256;                  // [256]
        hist[tid] = 0;
        __syncthreads();
        int e0 = blockIdx.x * CHUNK;
        int cnt = min(CHUNK, E - e0);
        for (int i = tid; i < cnt; i += 256) {
            int d = edst[e0 + i], s = esrc[e0 + i];
            stage[i] = ((unsigned)d << 16) | (unsigned)s;
            atomicAdd(&hist[d >> 8], 1);
        }
        __syncthreads();
        int h = hist[tid];
        base[tid] = h ? (tid * CAP + atomicAdd(&bcursor[tid], h)) : 0;
        cur[tid] = 0;
        __syncthreads();
        for (int i = tid; i < cnt; i += 256) {
            unsigned pk = stage[i];
            int b = pk >> 24;
            int p = base[b] + atomicAdd(&cur[b], 1);
            bsorted[p] = pk;
        }
    } else {
        // ---- layer-0 dual GEMM from fp32 features ----
        unsigned short (*xs)[136] = (unsigned short(*)[136])smem;
        int br = (blockIdx.x - ech) << 6;
        #pragma unroll
        for (int it = 0; it < 4; ++it) {
            int idx = tid + it * 256;
            int row = idx >> 4;
            int co = (idx & 15) << 3;
            int n = br + row;
            uint4 pk = make_uint4(0, 0, 0, 0);
            if (n < N) {
                float4 v0 = *(const float4*)(Xf + (size_t)n * 128 + co);
                float4 v1 = *(const float4*)(Xf + (size_t)n * 128 + co + 4);
                pk.x = (unsigned)f2bf(v0.x) | ((unsigned)f2bf(v0.y) << 16);
                pk.y = (unsigned)f2bf(v0.z) | ((unsigned)f2bf(v0.w) << 16);
                pk.z = (unsigned)f2bf(v1.x) | ((unsigned)f2bf(v1.y) << 16);
                pk.w = (unsigned)f2bf(v1.z) | ((unsigned)f2bf(v1.w) << 16);
            }
            *(uint4*)&xs[row][co] = pk;
        }
        __syncthreads();
        int wave = tid >> 6;
        int lane = tid & 63;
        int lrow = lane & 15;
        int kg = lane >> 4;
        int colbase = wave << 5;
        f32x4 acc[4][2][2];
        #pragma unroll
        for (int r = 0; r < 4; ++r)
            #pragma unroll
            for (int c = 0; c < 2; ++c) {
                acc[r][c][0] = (f32x4){0.f, 0.f, 0.f, 0.f};
                acc[r][c][1] = (f32x4){0.f, 0.f, 0.f, 0.f};
            }
        #pragma unroll
        for (int ks = 0; ks < 4; ++ks) {
            int kb = ks * 32 + kg * 8;
            bf16x8 af[4];
            #pragma unroll
            for (int r = 0; r < 4; ++r) af[r] = *(const bf16x8*)&xs[r * 16 + lrow][kb];
            bf16x8 bS[2], bN[2];
            #pragma unroll
            for (int c = 0; c < 2; ++c) {
                int col = colbase + c * 16 + lrow;
                bS[c] = *(const bf16x8*)(WsT + (size_t)col * 128 + kb);
                bN[c] = *(const bf16x8*)(WnT + (size_t)col * 128 + kb);
            }
            #pragma unroll
            for (int r = 0; r < 4; ++r)
                #pragma unroll
                for (int c = 0; c < 2; ++c) {
                    acc[r][c][0] = __builtin_amdgcn_mfma_f32_16x16x32_bf16(af[r], bS[c], acc[r][c][0], 0, 0, 0);
                    acc[r][c][1] = __builtin_amdgcn_mfma_f32_16x16x32_bf16(af[r], bN[c], acc[r][c][1], 0, 0, 0);
                }
        }
        #pragma unroll
        for (int r = 0; r < 4; ++r)
            #pragma unroll
            for (int c = 0; c < 2; ++c) {
                int col = colbase + c * 16 + lrow;
                float bv = bias[col];
                #pragma unroll
                for (int q = 0; q < 4; ++q) {
                    int n = br + r * 16 + kg * 4 + q;
                    if (n < N) {
                        Ab[(size_t)n * 128 + col] = f2bf(acc[r][c][0][q] + bv);
                        Tb[(size_t)n * 128 + col] = f2bf(acc[r][c][1][q]);
                    }
                }
            }
    }
}

// ---------- K3: per-bucket CSR finalize (fixed regions); csr = pre-scaled uint offsets ----------
__global__ __launch_bounds__(256) void k_bucket_csr(const unsigned* __restrict__ bsorted,
                                                    const int* __restrict__ bcursor,
                                                    int2* __restrict__ rbe,
                                                    float* __restrict__ dinv,
                                                    int* __restrict__ csr, int N) {
    __shared__ int sh[256];
    __shared__ int cur[256];
    int tid = threadIdx.x;
    int b = blockIdx.x;
    int lo = b * CAP;
    int hi = lo + bcursor[b];
    sh[tid] = 0;
    __syncthreads();
    for (int i = lo + tid; i < hi; i += 256) atomicAdd(&sh[(bsorted[i] >> 16) & 255], 1);
    __syncthreads();
    int v = sh[tid];
    __syncthreads();
    sh[tid] = v;
    __syncthreads();
    for (int off = 1; off < 256; off <<= 1) {
        int t = (tid >= off) ? sh[tid - off] : 0;
        __syncthreads();
        sh[tid] += t;
        __syncthreads();
    }
    int excl = sh[tid] - v;
    int d = (b << 8) + tid;
    if (d < N) {
        rbe[d] = make_int2(lo + excl, lo + excl + v);
        dinv[d] = 1.0f / (float)(v > 1 ? v : 1);
    }
    cur[tid] = lo + excl;
    __syncthreads();
    for (int i = lo + tid; i < hi; i += 256) {
        unsigned pk = bsorted[i];
        int p = atomicAdd(&cur[(pk >> 16) & 255], 1);
        csr[p] = (int)(pk & 0xffffu) << 6;
    }
}

// ---------- MFMA dual GEMM, bf16 input ----------
__global__ __launch_bounds__(256) void k_mfma_dual(
    const unsigned short* __restrict__ Xin,
    const unsigned short* __restrict__ WsT, const unsigned short* __restrict__ WnT,
    const float* __restrict__ bias, unsigned short* __restrict__ Ab,
    unsigned short* __restrict__ Tb, int N) {
    __shared__ unsigned short xs[64][136];
    int tid = threadIdx.x;
    int br = blockIdx.x << 6;
    #pragma unroll
    for (int it = 0; it < 4; ++it) {
        int idx = tid + it * 256;
        int row = idx >> 4;
        int co = (idx & 15) << 3;
        int n = br + row;
        uint4 pk = make_uint4(0, 0, 0, 0);
        if (n < N) pk = *(const uint4*)(Xin + (size_t)n * 128 + co);
        *(uint4*)&xs[row][co] = pk;
    }
    __syncthreads();
    int wave = tid >> 6;
    int lane = tid & 63;
    int lrow = lane & 15;
    int kg = lane >> 4;
    int colbase = wave << 5;
    f32x4 acc[4][2][2];
    #pragma unroll
    for (int r = 0; r < 4; ++r)
        #pragma unroll
        for (int c = 0; c < 2; ++c) {
            acc[r][c][0] = (f32x4){0.f, 0.f, 0.f, 0.f};
            acc[r][c][1] = (f32x4){0.f, 0.f, 0.f, 0.f};
        }
    #pragma unroll
    for (int ks = 0; ks < 4; ++ks) {
        int kb = ks * 32 + kg * 8;
        bf16x8 af[4];
        #pragma unroll
        for (int r = 0; r < 4; ++r) af[r] = *(const bf16x8*)&xs[r * 16 + lrow][kb];
        bf16x8 bS[2], bN[2];
        #pragma unroll
        for (int c = 0; c < 2; ++c) {
            int col = colbase + c * 16 + lrow;
            bS[c] = *(const bf16x8*)(WsT + (size_t)col * 128 + kb);
            bN[c] = *(const bf16x8*)(WnT + (size_t)col * 128 + kb);
        }
        #pragma unroll
        for (int r = 0; r < 4; ++r)
            #pragma unroll
            for (int c = 0; c < 2; ++c) {
                acc[r][c][0] = __builtin_amdgcn_mfma_f32_16x16x32_bf16(af[r], bS[c], acc[r][c][0], 0, 0, 0);
                acc[r][c][1] = __builtin_amdgcn_mfma_f32_16x16x32_bf16(af[r], bN[c], acc[r][c][1], 0, 0, 0);
            }
    }
    #pragma unroll
    for (int r = 0; r < 4; ++r)
        #pragma unroll
        for (int c = 0; c < 2; ++c) {
            int col = colbase + c * 16 + lrow;
            float bv = bias[col];
            #pragma unroll
            for (int q = 0; q < 4; ++q) {
                int n = br + r * 16 + kg * 4 + q;
                if (n < N) {
                    Ab[(size_t)n * 128 + col] = f2bf(acc[r][c][0][q] + bv);
                    Tb[(size_t)n * 128 + col] = f2bf(acc[r][c][1][q]);
                }
            }
        }
}

// ---------- aggregation layers 0/1: Hb = bf16(relu(Ab + agg(Tb)*dinv)) ----------
__global__ __launch_bounds__(256) void k_agg_relu_bf16(
    const unsigned* __restrict__ Tv, const unsigned* __restrict__ Av,
    const float* __restrict__ dinv, const int2* __restrict__ rbe,
    const int* __restrict__ csr, unsigned* __restrict__ Hv, int N) {
    int w = (blockIdx.x * 256 + threadIdx.x) >> 6;
    int lane = threadIdx.x & 63;
    if (w >= N) return;
    int2 be = rbe[w];
    int e = be.x, ee = be.y;
    float ax = 0.f, ay = 0.f;
    for (; e + 16 <= ee; e += 16) {
        int o[16];
        #pragma unroll
        for (int j = 0; j < 16; ++j) o[j] = csr[e + j];
        unsigned v[16];
        #pragma unroll
        for (int j = 0; j < 16; ++j) v[j] = Tv[(size_t)o[j] + lane];
        #pragma unroll
        for (int j = 0; j < 16; ++j) { ax += bf2f(v[j] & 0xffff); ay += bf2f(v[j] >> 16); }
    }
    for (; e + 4 <= ee; e += 4) {
        int o[4];
        #pragma unroll
        for (int j = 0; j < 4; ++j) o[j] = csr[e + j];
        unsigned v[4];
        #pragma unroll
        for (int j = 0; j < 4; ++j) v[j] = Tv[(size_t)o[j] + lane];
        #pragma unroll
        for (int j = 0; j < 4; ++j) { ax += bf2f(v[j] & 0xffff); ay += bf2f(v[j] >> 16); }
    }
    for (; e < ee; ++e) {
        unsigned v0 = Tv[(size_t)csr[e] + lane];
        ax += bf2f(v0 & 0xffff);
        ay += bf2f(v0 >> 16);
    }
    float di = dinv[w];
    unsigned av = Av[(size_t)w * 64 + lane];
    float ox = fmaxf(bf2f(av & 0xffff) + ax * di, 0.f);
    float oy = fmaxf(bf2f(av >> 16) + ay * di, 0.f);
    Hv[(size_t)w * 64 + lane] = (unsigned)f2bf(ox) | ((unsigned)f2bf(oy) << 16);
}

// ---------- layer-2 MFMA: self sums -> Sb, neighbor transforms -> Tb ----------
__global__ __launch_bounds__(256) void k_mfma_layer2(
    const unsigned short* __restrict__ Hb, const float* __restrict__ NZ,
    const unsigned short* __restrict__ WTcat, const float* __restrict__ b2,
    unsigned short* __restrict__ Sb, unsigned short* __restrict__ Tb, int N) {
    __shared__ unsigned short xh[64][136];
    __shared__ unsigned short xz[64][136];
    int tid = threadIdx.x;
    int br = blockIdx.x << 6;
    #pragma unroll
    for (int it = 0; it < 4; ++it) {
        int idx = tid + it * 256;
        int row = idx >> 4;
        int co = (idx & 15) << 3;
        int n = br + row;
        uint4 ph = make_uint4(0, 0, 0, 0), pz = make_uint4(0, 0, 0, 0);
        if (n < N) {
            ph = *(const uint4*)(Hb + (size_t)n * 128 + co);
            float4 v0 = *(const float4*)(NZ + (size_t)n * 128 + co);
            float4 v1 = *(const float4*)(NZ + (size_t)n * 128 + co + 4);
            pz.x = (unsigned)f2bf(v0.x) | ((unsigned)f2bf(v0.y) << 16);
            pz.y = (unsigned)f2bf(v0.z) | ((unsigned)f2bf(v0.w) << 16);
            pz.z = (unsigned)f2bf(v1.x) | ((unsigned)f2bf(v1.y) << 16);
            pz.w = (unsigned)f2bf(v1.z) | ((unsigned)f2bf(v1.w) << 16);
        }
        *(uint4*)&xh[row][co] = ph;
        *(uint4*)&xz[row][co] = pz;
    }
    __syncthreads();
    int wave = tid >> 6;
    int lane = tid & 63;
    int lrow = lane & 15;
    int kg = lane >> 4;
    int colbase = wave << 5;
    f32x4 acc[4][2][2];
    #pragma unroll
    for (int r = 0; r < 4; ++r)
        #pragma unroll
        for (int c = 0; c < 2; ++c) {
            acc[r][c][0] = (f32x4){0.f, 0.f, 0.f, 0.f};
            acc[r][c][1] = (f32x4){0.f, 0.f, 0.f, 0.f};
        }
    #pragma unroll
    for (int ks = 0; ks < 4; ++ks) {
        int kb = ks * 32 + kg * 8;
        bf16x8 ah[4], az[4];
        #pragma unroll
        for (int r = 0; r < 4; ++r) {
            ah[r] = *(const bf16x8*)&xh[r * 16 + lrow][kb];
            az[r] = *(const bf16x8*)&xz[r * 16 + lrow][kb];
        }
        bf16x8 bw[2];
        #pragma unroll
        for (int c = 0; c < 2; ++c) {
            int col = colbase + c * 16 + lrow;
            bw[c] = *(const bf16x8*)(WTcat + (size_t)col * 128 + kb);
        }
        #pragma unroll
        for (int r = 0; r < 4; ++r)
            #pragma unroll
            for (int c = 0; c < 2; ++c) {
                acc[r][c][0] = __builtin_amdgcn_mfma_f32_16x16x32_bf16(ah[r], bw[c], acc[r][c][0], 0, 0, 0);
                acc[r][c][1] = __builtin_amdgcn_mfma_f32_16x16x32_bf16(az[r], bw[c], acc[r][c][1], 0, 0, 0);
            }
    }
    if (wave < 2) {
        #pragma unroll
        for (int r = 0; r < 4; ++r)
            #pragma unroll
            for (int c = 0; c < 2; ++c) {
                int j = colbase + c * 16 + lrow;
                float bv = b2[j];
                #pragma unroll
                for (int q = 0; q < 4; ++q) {
                    int n = br + r * 16 + kg * 4 + q;
                    if (n < N) {
                        float hs = acc[r][c][0][q] + bv;
                        float zs = acc[r][c][1][q];
                        unsigned pk = (unsigned)f2bf(hs) | ((unsigned)f2bf(hs + zs) << 16);
                        ((unsigned*)Sb)[(size_t)n * 64 + j] = pk;
                    }
                }
            }
    } else {
        #pragma unroll
        for (int r = 0; r < 4; ++r)
            #pragma unroll
            for (int c = 0; c < 2; ++c) {
                int j = colbase - 64 + c * 16 + lrow;
                #pragma unroll
                for (int q = 0; q < 4; ++q) {
                    int n = br + r * 16 + kg * 4 + q;
                    if (n < N) {
                        unsigned pk = (unsigned)f2bf(acc[r][c][0][q]) |
                                      ((unsigned)f2bf(acc[r][c][1][q]) << 16);
                        ((unsigned*)Tb)[(size_t)n * 64 + j] = pk;
                    }
                }
            }
    }
}

// ---------- layer-2 aggregation: out = self + agg ----------
__global__ __launch_bounds__(256) void k_agg_final2(
    const unsigned short* __restrict__ Tb, const unsigned short* __restrict__ Sb,
    const float* __restrict__ dinv, const int2* __restrict__ rbe,
    const int* __restrict__ csr, float* __restrict__ out, int N) {
    int w = (blockIdx.x * 256 + threadIdx.x) >> 6;
    int lane = threadIdx.x & 63;
    if (w >= N) return;
    int2 be = rbe[w];
    int e = be.x, ee = be.y;
    const unsigned* Tv = (const unsigned*)Tb;
    float ax = 0.f, ay = 0.f;
    for (; e + 16 <= ee; e += 16) {
        int o[16];
        #pragma unroll
        for (int j = 0; j < 16; ++j) o[j] = csr[e + j];
        unsigned v[16];
        #pragma unroll
        for (int j = 0; j < 16; ++j) v[j] = Tv[(size_t)o[j] + lane];
        #pragma unroll
        for (int j = 0; j < 16; ++j) { ax += bf2f(v[j] & 0xffff); ay += bf2f(v[j] >> 16); }
    }
    for (; e + 4 <= ee; e += 4) {
        int o[4];
        #pragma unroll
        for (int j = 0; j < 4; ++j) o[j] = csr[e + j];
        unsigned v[4];
        #pragma unroll
        for (int j = 0; j < 4; ++j) v[j] = Tv[(size_t)o[j] + lane];
        #pragma unroll
        for (int j = 0; j < 4; ++j) { ax += bf2f(v[j] & 0xffff); ay += bf2f(v[j] >> 16); }
    }
    for (; e < ee; ++e) {
        unsigned v0 = Tv[(size_t)csr[e] + lane];
        ax += bf2f(v0 & 0xffff);
        ay += bf2f(v0 >> 16);
    }
    float di = dinv[w];
    unsigned sv = ((const unsigned*)Sb)[(size_t)w * 64 + lane];
    float* orow = out + (size_t)w * 128;
    orow[64 + lane] = bf2f(sv & 0xffff) + ax * di;
    orow[lane]      = bf2f(sv >> 16) + (ax + ay) * di;
}

extern "C" void kernel_launch(void* const* d_in, const int* in_sizes, int n_in,
                              void* d_out, int out_size, void* d_ws, size_t ws_size,
                              hipStream_t stream) {
    const float* features = (const float*)d_in[0];
    const float* noise    = (const float*)d_in[1];
    const float* Ws0 = (const float*)d_in[2];
    const float* Wn0 = (const float*)d_in[3];
    const float* b0  = (const float*)d_in[4];
    const float* Ws1 = (const float*)d_in[5];
    const float* Wn1 = (const float*)d_in[6];
    const float* b1  = (const float*)d_in[7];
    const float* Ws2 = (const float*)d_in[8];
    const float* Wn2 = (const float*)d_in[9];
    const float* b2  = (const float*)d_in[10];
    const int* esrc = (const int*)d_in[11];
    const int* edst = (const int*)d_in[12];
    int N = in_sizes[0] / 128;
    int E = in_sizes[11];
    float* out = (float*)d_out;

    // workspace
    unsigned short* Ab = (unsigned short*)d_ws;            // [N][128] bf16
    unsigned short* Tb = Ab + (size_t)N * 128;             // [N][128] bf16
    unsigned short* Hb = Tb + (size_t)N * 128;             // [N][128] bf16
    unsigned short* Sb = Hb + (size_t)N * 128;             // [N][128] bf16 (pairs)
    unsigned short* WT0s = Sb + (size_t)N * 128;
    unsigned short* WT0n = WT0s + 128 * 128;
    unsigned short* WT1s = WT0n + 128 * 128;
    unsigned short* WT1n = WT1s + 128 * 128;
    unsigned short* WT2  = WT1n + 128 * 128;
    float* dinv = (float*)(WT2 + 128 * 128);               // [N]
    int2* rbe  = (int2*)(dinv + N);                        // [N]
    int* csr   = (int*)(rbe + N);                          // [256*CAP]
    unsigned* bsorted = (unsigned*)(csr + 256 * CAP);      // [256*CAP]
    int* bcursor = (int*)(bsorted + 256 * CAP);            // [256]

    int nbk = (N + 255) >> 8;
    int ech = (E + CHUNK - 1) / CHUNK;
    int g64 = (N + 63) / 64;

    // K1: weight transpose (+ zero bcursor in block 0)
    k_wt<<<320, 256, 0, stream>>>(Ws0, Wn0, Ws1, Wn1, Ws2, Wn2,
                                  WT0s, WT0n, WT1s, WT1n, WT2, bcursor);
    // K2: bucket scatter (first) || layer-0 GEMM
    k_scatter_gemm0<<<ech + g64, 256, 0, stream>>>(esrc, edst, bcursor, bsorted, E, ech,
                                                   features, WT0s, WT0n, b0, Ab, Tb, N);
    // K3: per-bucket CSR finalize
    k_bucket_csr<<<nbk, 256, 0, stream>>>(bsorted, bcursor, rbe, dinv, csr, N);

    int ablocks = (N * 64 + 255) / 256;

    k_agg_relu_bf16<<<ablocks, 256, 0, stream>>>((const unsigned*)Tb, (const unsigned*)Ab,
                                                 dinv, rbe, csr, (unsigned*)Hb, N);
    k_mfma_dual<<<g64, 256, 0, stream>>>(Hb, WT1s, WT1n, b1, Ab, Tb, N);
    k_agg_relu_bf16<<<ablocks, 256, 0, stream>>>((const unsigned*)Tb, (const unsigned*)Ab,
                                                 dinv, rbe, csr, (unsigned*)Hb, N);
    k_mfma_layer2<<<g64, 256, 0, stream>>>(Hb, noise, WT2, b2, Sb, Tb, N);
    k_agg_final2<<<ablocks, 256, 0, stream>>>(Tb, Sb, dinv, rbe, csr, out, N);
}

// Round 12
// 180.943 us; speedup vs baseline: 1.4242x; 1.0719x over previous
//
#include <hip/hip_runtime.h>

typedef __attribute__((ext_vector_type(8))) short bf16x8;
typedef __attribute__((ext_vector_type(4))) float f32x4;
typedef __attribute__((ext_vector_type(2))) float f32x2;

__device__ __forceinline__ unsigned short f2bf(float x) {
    union { float f; unsigned u; } v; v.f = x;
    unsigned r = v.u + 0x7FFFu + ((v.u >> 16) & 1u);
    return (unsigned short)(r >> 16);
}
__device__ __forceinline__ float bf2f(unsigned u) {
    union { unsigned u; float f; } v; v.u = u << 16;
    return v.f;
}
__device__ __forceinline__ unsigned char f2fp8(float x) {
    return (unsigned char)(__builtin_amdgcn_cvt_pk_fp8_f32(x, x, 0, false) & 0xff);
}

#define CHUNK 4096
#define CAP 4608

// ---------- K1: weight transpose + zero bcursor ----------
__global__ __launch_bounds__(256) void k_wt(
    const float* __restrict__ Ws0, const float* __restrict__ Wn0,
    const float* __restrict__ Ws1, const float* __restrict__ Wn1,
    const float* __restrict__ Ws2, const float* __restrict__ Wn2,
    unsigned short* __restrict__ WT0s, unsigned short* __restrict__ WT0n,
    unsigned short* __restrict__ WT1s, unsigned short* __restrict__ WT1n,
    unsigned short* __restrict__ WT2, int* __restrict__ bcursor) {
    int tid = threadIdx.x;
    if (blockIdx.x == 0) bcursor[tid] = 0;
    int i = blockIdx.x * 256 + tid;
    if (i < 16384)      { int j = i;         WT0s[j] = f2bf(Ws0[(j & 127) * 128 + (j >> 7)]); }
    else if (i < 32768) { int j = i - 16384; WT0n[j] = f2bf(Wn0[(j & 127) * 128 + (j >> 7)]); }
    else if (i < 49152) { int j = i - 32768; WT1s[j] = f2bf(Ws1[(j & 127) * 128 + (j >> 7)]); }
    else if (i < 65536) { int j = i - 49152; WT1n[j] = f2bf(Wn1[(j & 127) * 128 + (j >> 7)]); }
    else if (i < 73728) { int j = i - 65536; WT2[j] = f2bf(Ws2[(j & 127) * 64 + (j >> 7)]); }
    else if (i < 81920) { int j = i - 73728; WT2[8192 + j] = f2bf(Wn2[(j & 127) * 64 + (j >> 7)]); }
}

// ---------- K2: bucket scatter (blocks < ech) UNION layer-0 GEMM ----------
__global__ __launch_bounds__(256) void k_scatter_gemm0(
    const int* __restrict__ esrc, const int* __restrict__ edst,
    int* __restrict__ bcursor, unsigned* __restrict__ bsorted, int E, int ech,
    const float* __restrict__ Xf,
    const unsigned short* __restrict__ WsT, const unsigned short* __restrict__ WnT,
    const float* __restrict__ bias, unsigned short* __restrict__ Ab,
    unsigned char* __restrict__ T8, int N) {
    __shared__ uint4 smem[1216];
    int tid = threadIdx.x;
    if ((int)blockIdx.x < ech) {
        unsigned* stage = (unsigned*)smem;
        int* hist = (int*)(stage + CHUNK);
        int* base = hist + 256;
        int* cur  = base + 256;
        hist[tid] = 0;
        __syncthreads();
        int e0 = blockIdx.x * CHUNK;
        int cnt = min(CHUNK, E - e0);
        for (int i = tid; i < cnt; i += 256) {
            int d = edst[e0 + i], s = esrc[e0 + i];
            stage[i] = ((unsigned)d << 16) | (unsigned)s;
            atomicAdd(&hist[d >> 8], 1);
        }
        __syncthreads();
        int h = hist[tid];
        base[tid] = h ? (tid * CAP + atomicAdd(&bcursor[tid], h)) : 0;
        cur[tid] = 0;
        __syncthreads();
        for (int i = tid; i < cnt; i += 256) {
            unsigned pk = stage[i];
            int b = pk >> 24;
            int p = base[b] + atomicAdd(&cur[b], 1);
            bsorted[p] = pk;
        }
    } else {
        unsigned short (*xs)[136] = (unsigned short(*)[136])smem;
        int br = (blockIdx.x - ech) << 6;
        #pragma unroll
        for (int it = 0; it < 4; ++it) {
            int idx = tid + it * 256;
            int row = idx >> 4;
            int co = (idx & 15) << 3;
            int n = br + row;
            uint4 pk = make_uint4(0, 0, 0, 0);
            if (n < N) {
                float4 v0 = *(const float4*)(Xf + (size_t)n * 128 + co);
                float4 v1 = *(const float4*)(Xf + (size_t)n * 128 + co + 4);
                pk.x = (unsigned)f2bf(v0.x) | ((unsigned)f2bf(v0.y) << 16);
                pk.y = (unsigned)f2bf(v0.z) | ((unsigned)f2bf(v0.w) << 16);
                pk.z = (unsigned)f2bf(v1.x) | ((unsigned)f2bf(v1.y) << 16);
                pk.w = (unsigned)f2bf(v1.z) | ((unsigned)f2bf(v1.w) << 16);
            }
            *(uint4*)&xs[row][co] = pk;
        }
        __syncthreads();
        int wave = tid >> 6;
        int lane = tid & 63;
        int lrow = lane & 15;
        int kg = lane >> 4;
        int colbase = wave << 5;
        f32x4 acc[4][2][2];
        #pragma unroll
        for (int r = 0; r < 4; ++r)
            #pragma unroll
            for (int c = 0; c < 2; ++c) {
                acc[r][c][0] = (f32x4){0.f, 0.f, 0.f, 0.f};
                acc[r][c][1] = (f32x4){0.f, 0.f, 0.f, 0.f};
            }
        #pragma unroll
        for (int ks = 0; ks < 4; ++ks) {
            int kb = ks * 32 + kg * 8;
            bf16x8 af[4];
            #pragma unroll
            for (int r = 0; r < 4; ++r) af[r] = *(const bf16x8*)&xs[r * 16 + lrow][kb];
            bf16x8 bS[2], bN[2];
            #pragma unroll
            for (int c = 0; c < 2; ++c) {
                int col = colbase + c * 16 + lrow;
                bS[c] = *(const bf16x8*)(WsT + (size_t)col * 128 + kb);
                bN[c] = *(const bf16x8*)(WnT + (size_t)col * 128 + kb);
            }
            #pragma unroll
            for (int r = 0; r < 4; ++r)
                #pragma unroll
                for (int c = 0; c < 2; ++c) {
                    acc[r][c][0] = __builtin_amdgcn_mfma_f32_16x16x32_bf16(af[r], bS[c], acc[r][c][0], 0, 0, 0);
                    acc[r][c][1] = __builtin_amdgcn_mfma_f32_16x16x32_bf16(af[r], bN[c], acc[r][c][1], 0, 0, 0);
                }
        }
        #pragma unroll
        for (int r = 0; r < 4; ++r)
            #pragma unroll
            for (int c = 0; c < 2; ++c) {
                int col = colbase + c * 16 + lrow;
                float bv = bias[col];
                #pragma unroll
                for (int q = 0; q < 4; ++q) {
                    int n = br + r * 16 + kg * 4 + q;
                    if (n < N) {
                        Ab[(size_t)n * 128 + col] = f2bf(acc[r][c][0][q] + bv);
                        T8[(size_t)n * 128 + col] = f2fp8(acc[r][c][1][q]);
                    }
                }
            }
    }
}

// ---------- K3: per-bucket CSR finalize; csr = pre-scaled ushort-offsets (src<<6) ----------
__global__ __launch_bounds__(256) void k_bucket_csr(const unsigned* __restrict__ bsorted,
                                                    const int* __restrict__ bcursor,
                                                    int2* __restrict__ rbe,
                                                    float* __restrict__ dinv,
                                                    int* __restrict__ csr, int N) {
    __shared__ int sh[256];
    __shared__ int cur[256];
    int tid = threadIdx.x;
    int b = blockIdx.x;
    int lo = b * CAP;
    int hi = lo + bcursor[b];
    sh[tid] = 0;
    __syncthreads();
    for (int i = lo + tid; i < hi; i += 256) atomicAdd(&sh[(bsorted[i] >> 16) & 255], 1);
    __syncthreads();
    int v = sh[tid];
    __syncthreads();
    sh[tid] = v;
    __syncthreads();
    for (int off = 1; off < 256; off <<= 1) {
        int t = (tid >= off) ? sh[tid - off] : 0;
        __syncthreads();
        sh[tid] += t;
        __syncthreads();
    }
    int excl = sh[tid] - v;
    int d = (b << 8) + tid;
    if (d < N) {
        rbe[d] = make_int2(lo + excl, lo + excl + v);
        dinv[d] = 1.0f / (float)(v > 1 ? v : 1);
    }
    cur[tid] = lo + excl;
    __syncthreads();
    for (int i = lo + tid; i < hi; i += 256) {
        unsigned pk = bsorted[i];
        int p = atomicAdd(&cur[(pk >> 16) & 255], 1);
        csr[p] = (int)(pk & 0xffffu) << 6;
    }
}

// ---------- MFMA dual GEMM, bf16 input: Ab = bf16(X@Ws+b), T8 = fp8(X@Wn) ----------
__global__ __launch_bounds__(256) void k_mfma_dual(
    const unsigned short* __restrict__ Xin,
    const unsigned short* __restrict__ WsT, const unsigned short* __restrict__ WnT,
    const float* __restrict__ bias, unsigned short* __restrict__ Ab,
    unsigned char* __restrict__ T8, int N) {
    __shared__ unsigned short xs[64][136];
    int tid = threadIdx.x;
    int br = blockIdx.x << 6;
    #pragma unroll
    for (int it = 0; it < 4; ++it) {
        int idx = tid + it * 256;
        int row = idx >> 4;
        int co = (idx & 15) << 3;
        int n = br + row;
        uint4 pk = make_uint4(0, 0, 0, 0);
        if (n < N) pk = *(const uint4*)(Xin + (size_t)n * 128 + co);
        *(uint4*)&xs[row][co] = pk;
    }
    __syncthreads();
    int wave = tid >> 6;
    int lane = tid & 63;
    int lrow = lane & 15;
    int kg = lane >> 4;
    int colbase = wave << 5;
    f32x4 acc[4][2][2];
    #pragma unroll
    for (int r = 0; r < 4; ++r)
        #pragma unroll
        for (int c = 0; c < 2; ++c) {
            acc[r][c][0] = (f32x4){0.f, 0.f, 0.f, 0.f};
            acc[r][c][1] = (f32x4){0.f, 0.f, 0.f, 0.f};
        }
    #pragma unroll
    for (int ks = 0; ks < 4; ++ks) {
        int kb = ks * 32 + kg * 8;
        bf16x8 af[4];
        #pragma unroll
        for (int r = 0; r < 4; ++r) af[r] = *(const bf16x8*)&xs[r * 16 + lrow][kb];
        bf16x8 bS[2], bN[2];
        #pragma unroll
        for (int c = 0; c < 2; ++c) {
            int col = colbase + c * 16 + lrow;
            bS[c] = *(const bf16x8*)(WsT + (size_t)col * 128 + kb);
            bN[c] = *(const bf16x8*)(WnT + (size_t)col * 128 + kb);
        }
        #pragma unroll
        for (int r = 0; r < 4; ++r)
            #pragma unroll
            for (int c = 0; c < 2; ++c) {
                acc[r][c][0] = __builtin_amdgcn_mfma_f32_16x16x32_bf16(af[r], bS[c], acc[r][c][0], 0, 0, 0);
                acc[r][c][1] = __builtin_amdgcn_mfma_f32_16x16x32_bf16(af[r], bN[c], acc[r][c][1], 0, 0, 0);
            }
    }
    #pragma unroll
    for (int r = 0; r < 4; ++r)
        #pragma unroll
        for (int c = 0; c < 2; ++c) {
            int col = colbase + c * 16 + lrow;
            float bv = bias[col];
            #pragma unroll
            for (int q = 0; q < 4; ++q) {
                int n = br + r * 16 + kg * 4 + q;
                if (n < N) {
                    Ab[(size_t)n * 128 + col] = f2bf(acc[r][c][0][q] + bv);
                    T8[(size_t)n * 128 + col] = f2fp8(acc[r][c][1][q]);
                }
            }
        }
}

// ---------- agg layers 0/1: Hb = bf16(relu(Ab + agg(T8)*dinv)); T8 rows = 128 B fp8 ----------
__global__ __launch_bounds__(256) void k_agg_relu(
    const unsigned short* __restrict__ T8p, const unsigned* __restrict__ Av,
    const float* __restrict__ dinv, const int2* __restrict__ rbe,
    const int* __restrict__ csr, unsigned* __restrict__ Hv, int N) {
    int w = (blockIdx.x * 256 + threadIdx.x) >> 6;
    int lane = threadIdx.x & 63;
    if (w >= N) return;
    int2 be = rbe[w];
    int e = be.x, ee = be.y;
    float ax = 0.f, ay = 0.f;
    for (; e + 16 <= ee; e += 16) {
        int o[16];
        #pragma unroll
        for (int j = 0; j < 16; ++j) o[j] = csr[e + j];
        unsigned short v[16];
        #pragma unroll
        for (int j = 0; j < 16; ++j) v[j] = T8p[(size_t)o[j] + lane];
        #pragma unroll
        for (int j = 0; j < 16; ++j) {
            f32x2 d = __builtin_amdgcn_cvt_pk_f32_fp8((unsigned)v[j], false);
            ax += d.x; ay += d.y;
        }
    }
    for (; e + 4 <= ee; e += 4) {
        int o[4];
        #pragma unroll
        for (int j = 0; j < 4; ++j) o[j] = csr[e + j];
        unsigned short v[4];
        #pragma unroll
        for (int j = 0; j < 4; ++j) v[j] = T8p[(size_t)o[j] + lane];
        #pragma unroll
        for (int j = 0; j < 4; ++j) {
            f32x2 d = __builtin_amdgcn_cvt_pk_f32_fp8((unsigned)v[j], false);
            ax += d.x; ay += d.y;
        }
    }
    for (; e < ee; ++e) {
        f32x2 d = __builtin_amdgcn_cvt_pk_f32_fp8((unsigned)T8p[(size_t)csr[e] + lane], false);
        ax += d.x; ay += d.y;
    }
    float di = dinv[w];
    unsigned av = Av[(size_t)w * 64 + lane];
    float ox = fmaxf(bf2f(av & 0xffff) + ax * di, 0.f);
    float oy = fmaxf(bf2f(av >> 16) + ay * di, 0.f);
    Hv[(size_t)w * 64 + lane] = (unsigned)f2bf(ox) | ((unsigned)f2bf(oy) << 16);
}

// ---------- layer-2 MFMA: self sums -> Sb (bf16 pairs), neighbor pairs -> T8 (fp8 pairs) ----------
__global__ __launch_bounds__(256) void k_mfma_layer2(
    const unsigned short* __restrict__ Hb, const float* __restrict__ NZ,
    const unsigned short* __restrict__ WTcat, const float* __restrict__ b2,
    unsigned short* __restrict__ Sb, unsigned short* __restrict__ T8p, int N) {
    __shared__ unsigned short xh[64][136];
    __shared__ unsigned short xz[64][136];
    int tid = threadIdx.x;
    int br = blockIdx.x << 6;
    #pragma unroll
    for (int it = 0; it < 4; ++it) {
        int idx = tid + it * 256;
        int row = idx >> 4;
        int co = (idx & 15) << 3;
        int n = br + row;
        uint4 ph = make_uint4(0, 0, 0, 0), pz = make_uint4(0, 0, 0, 0);
        if (n < N) {
            ph = *(const uint4*)(Hb + (size_t)n * 128 + co);
            float4 v0 = *(const float4*)(NZ + (size_t)n * 128 + co);
            float4 v1 = *(const float4*)(NZ + (size_t)n * 128 + co + 4);
            pz.x = (unsigned)f2bf(v0.x) | ((unsigned)f2bf(v0.y) << 16);
            pz.y = (unsigned)f2bf(v0.z) | ((unsigned)f2bf(v0.w) << 16);
            pz.z = (unsigned)f2bf(v1.x) | ((unsigned)f2bf(v1.y) << 16);
            pz.w = (unsigned)f2bf(v1.z) | ((unsigned)f2bf(v1.w) << 16);
        }
        *(uint4*)&xh[row][co] = ph;
        *(uint4*)&xz[row][co] = pz;
    }
    __syncthreads();
    int wave = tid >> 6;
    int lane = tid & 63;
    int lrow = lane & 15;
    int kg = lane >> 4;
    int colbase = wave << 5;
    f32x4 acc[4][2][2];
    #pragma unroll
    for (int r = 0; r < 4; ++r)
        #pragma unroll
        for (int c = 0; c < 2; ++c) {
            acc[r][c][0] = (f32x4){0.f, 0.f, 0.f, 0.f};
            acc[r][c][1] = (f32x4){0.f, 0.f, 0.f, 0.f};
        }
    #pragma unroll
    for (int ks = 0; ks < 4; ++ks) {
        int kb = ks * 32 + kg * 8;
        bf16x8 ah[4], az[4];
        #pragma unroll
        for (int r = 0; r < 4; ++r) {
            ah[r] = *(const bf16x8*)&xh[r * 16 + lrow][kb];
            az[r] = *(const bf16x8*)&xz[r * 16 + lrow][kb];
        }
        bf16x8 bw[2];
        #pragma unroll
        for (int c = 0; c < 2; ++c) {
            int col = colbase + c * 16 + lrow;
            bw[c] = *(const bf16x8*)(WTcat + (size_t)col * 128 + kb);
        }
        #pragma unroll
        for (int r = 0; r < 4; ++r)
            #pragma unroll
            for (int c = 0; c < 2; ++c) {
                acc[r][c][0] = __builtin_amdgcn_mfma_f32_16x16x32_bf16(ah[r], bw[c], acc[r][c][0], 0, 0, 0);
                acc[r][c][1] = __builtin_amdgcn_mfma_f32_16x16x32_bf16(az[r], bw[c], acc[r][c][1], 0, 0, 0);
            }
    }
    if (wave < 2) {
        #pragma unroll
        for (int r = 0; r < 4; ++r)
            #pragma unroll
            for (int c = 0; c < 2; ++c) {
                int j = colbase + c * 16 + lrow;
                float bv = b2[j];
                #pragma unroll
                for (int q = 0; q < 4; ++q) {
                    int n = br + r * 16 + kg * 4 + q;
                    if (n < N) {
                        float hs = acc[r][c][0][q] + bv;
                        float zs = acc[r][c][1][q];
                        unsigned pk = (unsigned)f2bf(hs) | ((unsigned)f2bf(hs + zs) << 16);
                        ((unsigned*)Sb)[(size_t)n * 64 + j] = pk;
                    }
                }
            }
    } else {
        #pragma unroll
        for (int r = 0; r < 4; ++r)
            #pragma unroll
            for (int c = 0; c < 2; ++c) {
                int j = colbase - 64 + c * 16 + lrow;
                #pragma unroll
                for (int q = 0; q < 4; ++q) {
                    int n = br + r * 16 + kg * 4 + q;
                    if (n < N) {
                        unsigned pk = __builtin_amdgcn_cvt_pk_fp8_f32(
                            acc[r][c][0][q], acc[r][c][1][q], 0, false);
                        T8p[(size_t)n * 64 + j] = (unsigned short)(pk & 0xffffu);
                    }
                }
            }
    }
}

// ---------- layer-2 aggregation: out = self + agg(fp8 pairs) ----------
__global__ __launch_bounds__(256) void k_agg_final2(
    const unsigned short* __restrict__ T8p, const unsigned short* __restrict__ Sb,
    const float* __restrict__ dinv, const int2* __restrict__ rbe,
    const int* __restrict__ csr, float* __restrict__ out, int N) {
    int w = (blockIdx.x * 256 + threadIdx.x) >> 6;
    int lane = threadIdx.x & 63;
    if (w >= N) return;
    int2 be = rbe[w];
    int e = be.x, ee = be.y;
    float ax = 0.f, ay = 0.f;
    for (; e + 16 <= ee; e += 16) {
        int o[16];
        #pragma unroll
        for (int j = 0; j < 16; ++j) o[j] = csr[e + j];
        unsigned short v[16];
        #pragma unroll
        for (int j = 0; j < 16; ++j) v[j] = T8p[(size_t)o[j] + lane];
        #pragma unroll
        for (int j = 0; j < 16; ++j) {
            f32x2 d = __builtin_amdgcn_cvt_pk_f32_fp8((unsigned)v[j], false);
            ax += d.x; ay += d.y;
        }
    }
    for (; e + 4 <= ee; e += 4) {
        int o[4];
        #pragma unroll
        for (int j = 0; j < 4; ++j) o[j] = csr[e + j];
        unsigned short v[4];
        #pragma unroll
        for (int j = 0; j < 4; ++j) v[j] = T8p[(size_t)o[j] + lane];
        #pragma unroll
        for (int j = 0; j < 4; ++j) {
            f32x2 d = __builtin_amdgcn_cvt_pk_f32_fp8((unsigned)v[j], false);
            ax += d.x; ay += d.y;
        }
    }
    for (; e < ee; ++e) {
        f32x2 d = __builtin_amdgcn_cvt_pk_f32_fp8((unsigned)T8p[(size_t)csr[e] + lane], false);
        ax += d.x; ay += d.y;
    }
    float di = dinv[w];
    unsigned sv = ((const unsigned*)Sb)[(size_t)w * 64 + lane];
    float* orow = out + (size_t)w * 128;
    orow[64 + lane] = bf2f(sv & 0xffff) + ax * di;     // h2 = self + agg(h1@Wn2)/deg
    orow[lane]      = bf2f(sv >> 16) + (ax + ay) * di; // hn2 = self + agg((h1+nz)@Wn2)/deg
}

extern "C" void kernel_launch(void* const* d_in, const int* in_sizes, int n_in,
                              void* d_out, int out_size, void* d_ws, size_t ws_size,
                              hipStream_t stream) {
    const float* features = (const float*)d_in[0];
    const float* noise    = (const float*)d_in[1];
    const float* Ws0 = (const float*)d_in[2];
    const float* Wn0 = (const float*)d_in[3];
    const float* b0  = (const float*)d_in[4];
    const float* Ws1 = (const float*)d_in[5];
    const float* Wn1 = (const float*)d_in[6];
    const float* b1  = (const float*)d_in[7];
    const float* Ws2 = (const float*)d_in[8];
    const float* Wn2 = (const float*)d_in[9];
    const float* b2  = (const float*)d_in[10];
    const int* esrc = (const int*)d_in[11];
    const int* edst = (const int*)d_in[12];
    int N = in_sizes[0] / 128;
    int E = in_sizes[11];
    float* out = (float*)d_out;

    // workspace
    unsigned short* Ab = (unsigned short*)d_ws;            // [N][128] bf16
    unsigned short* Hb = Ab + (size_t)N * 128;             // [N][128] bf16
    unsigned short* Sb = Hb + (size_t)N * 128;             // [N][64] bf16 pairs
    unsigned char*  T8 = (unsigned char*)(Sb + (size_t)N * 128); // [N][128] fp8 (or [N][64] pairs)
    unsigned short* WT0s = (unsigned short*)(T8 + (size_t)N * 128);
    unsigned short* WT0n = WT0s + 128 * 128;
    unsigned short* WT1s = WT0n + 128 * 128;
    unsigned short* WT1n = WT1s + 128 * 128;
    unsigned short* WT2  = WT1n + 128 * 128;
    float* dinv = (float*)(WT2 + 128 * 128);               // [N]
    int2* rbe  = (int2*)(dinv + N);                        // [N]
    int* csr   = (int*)(rbe + N);                          // [256*CAP]
    unsigned* bsorted = (unsigned*)(csr + 256 * CAP);      // [256*CAP]
    int* bcursor = (int*)(bsorted + 256 * CAP);            // [256]

    int nbk = (N + 255) >> 8;
    int ech = (E + CHUNK - 1) / CHUNK;
    int g64 = (N + 63) / 64;

    k_wt<<<320, 256, 0, stream>>>(Ws0, Wn0, Ws1, Wn1, Ws2, Wn2,
                                  WT0s, WT0n, WT1s, WT1n, WT2, bcursor);
    k_scatter_gemm0<<<ech + g64, 256, 0, stream>>>(esrc, edst, bcursor, bsorted, E, ech,
                                                   features, WT0s, WT0n, b0, Ab, T8, N);
    k_bucket_csr<<<nbk, 256, 0, stream>>>(bsorted, bcursor, rbe, dinv, csr, N);

    int ablocks = (N * 64 + 255) / 256;

    k_agg_relu<<<ablocks, 256, 0, stream>>>((const unsigned short*)T8, (const unsigned*)Ab,
                                            dinv, rbe, csr, (unsigned*)Hb, N);
    k_mfma_dual<<<g64, 256, 0, stream>>>(Hb, WT1s, WT1n, b1, Ab, T8, N);
    k_agg_relu<<<ablocks, 256, 0, stream>>>((const unsigned short*)T8, (const unsigned*)Ab,
                                            dinv, rbe, csr, (unsigned*)Hb, N);
    k_mfma_layer2<<<g64, 256, 0, stream>>>(Hb, noise, WT2, b2, Sb, (unsigned short*)T8, N);
    k_agg_final2<<<ablocks, 256, 0, stream>>>((const unsigned short*)T8, Sb, dinv, rbe, csr, out, N);
}